// Round 14
// baseline (412.573 us; speedup 1.0000x reference)
//
#include <hip/hip_runtime.h>
#include <hip/hip_fp16.h>

#define B 32
#define NW2V 300
#define NR 200
#define NBLK 256          // chunks for count/scatter passes
#define CBLOG 11          // coarse bucket = 2048 entities
#define CBSZ  2048
#define FNB   2048        // fine bins (11-bit counting sort)
#define FTE   128         // fused_front transpose tile (17KB LDS -> 8 blk/CU)
#define TBE   256         // transpose_out tile
#define ZBC   1024        // zero-blocks in fused_front (bufB+bufC, 64MB)
#define ZA    512         // zero-blocks in hop2 (bufA, 32MB)

// Fused front: [0,tblocks) transpose x->xT f16 in 128-entity tiles (blocks
// <NBLK also coarse-count one chunk); [tblocks,+3*NR) compute rT; tail ZBC
// blocks stream-zero bufB+bufC. Round-14: tile 256->128 entities (LDS 33->17
// KB -> 4->8 blocks/CU; round-13 profile: occupancy 36%, VALUBusy 4.6% --
// latency-bound on block-level overlap, not per-thread MLP).
__global__ void fused_front_kernel(const float* __restrict__ x,
                                   __half* __restrict__ xT, int n_e,
                                   const int* __restrict__ obj,
                                   int* __restrict__ hist_bb,
                                   int n_t, int nb, int chunk, int tblocks,
                                   const float* __restrict__ q,
                                   const float* __restrict__ W1, const float* __restrict__ b1,
                                   const float* __restrict__ W2, const float* __restrict__ b2,
                                   const float* __restrict__ W3, const float* __restrict__ b3,
                                   float* __restrict__ rT,
                                   float4* __restrict__ zptr, long zn4) {
    if (blockIdx.x >= tblocks + 3 * NR) {   // ---- zero bufB+bufC ----
        long zid = blockIdx.x - (tblocks + 3 * NR);
        float4 z4 = make_float4(0.f, 0.f, 0.f, 0.f);
        for (long i = zid * 256 + threadIdx.x; i < zn4; i += (long)ZBC * 256)
            zptr[i] = z4;
        return;
    }
    if (blockIdx.x >= tblocks) {      // ---- compute_r part (600 blocks) ----
        int bid = blockIdx.x - tblocks;
        int h = bid / NR;
        int j = bid % NR;
        const float* W    = (h == 0) ? W1 : (h == 1) ? W2 : W3;
        const float* bias = (h == 0) ? b1 : (h == 1) ? b2 : b3;
        int t = threadIdx.x;
        int b  = t & 31;
        int ks = t >> 5;              // 8 k-slices of <=38
        int k0 = ks * 38;
        int k1 = min(NW2V, k0 + 38);
        float acc = 0.f;
        for (int k = k0; k < k1; ++k)
            acc += q[b * NW2V + k] * W[k * NR + j];
        __shared__ float red[8][32];
        red[ks][b] = acc;
        __syncthreads();
        if (ks == 0) {
            float s = bias[j];
#pragma unroll
            for (int r = 0; r < 8; ++r) s += red[r][b];
            rT[h * NR * B + j * B + b] = s;
        }
        return;
    }
    // ---- transpose (+count) part: 128-entity tile, reg-staged bursts ----
    __shared__ float tile[32][133];   // stride 133 (5 mod 32): pack-reads
    __shared__ int h[256];            //   across bq*5 -> distinct banks
    int t = threadIdx.x;
    int e0 = blockIdx.x * FTE;
    bool full = (e0 + FTE <= n_e);
    if (full) {
        float4 v[4];                  // 64B in flight/thread; 8 blk/CU overlap
#pragma unroll
        for (int p = 0; p < 4; ++p) {
            int idx = p * 256 + t;
            int b = idx >> 5, e4 = (idx & 31) * 4;
            v[p] = *reinterpret_cast<const float4*>(&x[(size_t)b * n_e + e0 + e4]);
        }
#pragma unroll
        for (int p = 0; p < 4; ++p) {
            int idx = p * 256 + t;
            int b = idx >> 5, e4 = (idx & 31) * 4;
            tile[b][e4 + 0] = v[p].x; tile[b][e4 + 1] = v[p].y;
            tile[b][e4 + 2] = v[p].z; tile[b][e4 + 3] = v[p].w;
        }
    } else {
        for (int p = 0; p < 16; ++p) {
            int idx = p * 256 + t;
            int b = idx >> 7, e = idx & 127;
            tile[b][e] = (e0 + e < n_e) ? x[(size_t)b * n_e + e0 + e] : 0.f;
        }
    }
    __syncthreads();
    // write: 4 passes, 8B/thread (4 halves packed as uint2), line-coalesced
#pragma unroll
    for (int p = 0; p < 4; ++p) {
        int idx = p * 256 + t;
        int e = idx >> 3, bq = (idx & 7) * 4;
        if (full || e0 + e < n_e) {
            __half2 h0 = __floats2half2_rn(tile[bq + 0][e], tile[bq + 1][e]);
            __half2 h1 = __floats2half2_rn(tile[bq + 2][e], tile[bq + 3][e]);
            uint2 pk = make_uint2(*reinterpret_cast<unsigned*>(&h0),
                                  *reinterpret_cast<unsigned*>(&h1));
            *reinterpret_cast<uint2*>(xT + (size_t)(e0 + e) * 32 + bq) = pk;
        }
    }
    if (blockIdx.x < NBLK) {          // fused coarse count, 4-wide unroll
        h[t] = 0;
        __syncthreads();
        int t0 = blockIdx.x * chunk;
        int t1 = min(t0 + chunk, n_t);
        for (int i0 = t0 + t; i0 < t1; i0 += 1024) {
            int o0 = obj[i0];
            int o1 = (i0 + 256 < t1) ? obj[i0 + 256] : -1;
            int o2 = (i0 + 512 < t1) ? obj[i0 + 512] : -1;
            int o3 = (i0 + 768 < t1) ? obj[i0 + 768] : -1;
            atomicAdd(&h[o0 >> CBLOG], 1);
            if (o1 >= 0) atomicAdd(&h[o1 >> CBLOG], 1);
            if (o2 >= 0) atomicAdd(&h[o2 >> CBLOG], 1);
            if (o3 >= 0) atomicAdd(&h[o3 >> CBLOG], 1);
        }
        __syncthreads();
        if (t < nb)
            hist_bb[(size_t)t * NBLK + blockIdx.x] = h[t];
    }
}

// xT [N_E, B] f16 -> out [B, N_E] f32. Round-14: 4 staged float4 reads
// (same 64B/thread as 16 half2 but 4x fewer VMEM requests).
__global__ void transpose_out_kernel(const __half* __restrict__ xT,
                                     float* __restrict__ out, int n_e) {
    __shared__ float tile[256][33];   // (e + 8q) mod 32 -> 2-way = free
    int t = threadIdx.x;
    int e0 = blockIdx.x * TBE;
    bool full = (e0 + TBE <= n_e);
    if (full) {
        float4 v[4];
#pragma unroll
        for (int p = 0; p < 4; ++p) {
            int idx = p * 256 + t;
            int e = idx >> 2, qd = idx & 3;
            v[p] = reinterpret_cast<const float4*>(xT)[(size_t)(e0 + e) * 4 + qd];
        }
#pragma unroll
        for (int p = 0; p < 4; ++p) {
            int idx = p * 256 + t;
            int e = idx >> 2, qd = idx & 3;
            const __half2* hp = reinterpret_cast<const __half2*>(&v[p]);
#pragma unroll
            for (int j = 0; j < 4; ++j) {
                float2 f = __half22float2(hp[j]);
                tile[e][qd * 8 + 2 * j]     = f.x;
                tile[e][qd * 8 + 2 * j + 1] = f.y;
            }
        }
        __syncthreads();
#pragma unroll
        for (int p = 0; p < 8; ++p) {
            int idx = p * 256 + t;
            int b = idx >> 6, e4 = (idx & 63) * 4;
            float4 w = make_float4(tile[e4][b], tile[e4 + 1][b],
                                   tile[e4 + 2][b], tile[e4 + 3][b]);
            *reinterpret_cast<float4*>(&out[(size_t)b * n_e + e0 + e4]) = w;
        }
    } else {
        for (int p = 0; p < 16; ++p) {
            int idx = p * 256 + t;
            int e = idx >> 4, bp = idx & 15;
            if (e0 + e < n_e) {
                __half2 v = reinterpret_cast<const __half2*>(xT)[(size_t)(e0 + e) * 16 + bp];
                float2 f = __half22float2(v);
                tile[e][2 * bp]     = f.x;
                tile[e][2 * bp + 1] = f.y;
            }
        }
        __syncthreads();
        for (int p = 0; p < 32; ++p) {
            int idx = p * 256 + t;
            int b = idx >> 8, e = idx & 255;
            if (e0 + e < n_e)
                out[(size_t)b * n_e + e0 + e] = tile[e][b];
        }
    }
}

// One tiny block: per-bucket totals -> exclusive scan -> base[nb+1], gcur[nb].
__global__ void bucket_scan_kernel(const int* __restrict__ hist_bb,
                                   int* __restrict__ base,
                                   int* __restrict__ gcur, int nb) {
    __shared__ int ws[4];
    int t = threadIdx.x, wave = t >> 6, lane = t & 63;
    int tot = 0;
    if (t < nb) {
        const int4* p = reinterpret_cast<const int4*>(hist_bb + (size_t)t * NBLK);
        for (int c = 0; c < NBLK / 4; ++c) {
            int4 v = p[c];
            tot += v.x + v.y + v.z + v.w;
        }
    }
    int v = tot;
#pragma unroll
    for (int off = 1; off < 64; off <<= 1) {
        int u = __shfl_up(v, off, 64);
        if (lane >= off) v += u;
    }
    if (lane == 63) ws[wave] = v;
    __syncthreads();
    if (wave == 0 && lane < 4) {
        int w = ws[lane];
#pragma unroll
        for (int off = 1; off < 4; off <<= 1) {
            int u = __shfl_up(w, off, 64);
            if (lane >= off) w += u;
        }
        ws[lane] = w;
    }
    __syncthreads();
    int excl = (wave ? ws[wave - 1] : 0) + v - tot;
    if (t < nb) {
        base[t] = excl;
        gcur[t] = excl;
    }
    if (t == nb) base[t] = excl;      // total
}

// coarse scatter into 2048-entity buckets; atomic range reservation in gcur.
__global__ void scatter8_kernel(const int* __restrict__ subj,
                                const int* __restrict__ rel,
                                const int* __restrict__ obj,
                                int* __restrict__ gcur,
                                uint2* __restrict__ packed2,
                                int n_t, int nb, int chunk) {
    __shared__ int h[256];
    __shared__ int sbase[256];
    int tid = threadIdx.x;
    if (tid < 256) h[tid] = 0;
    __syncthreads();
    int t0 = blockIdx.x * chunk;
    int t1 = min(t0 + chunk, n_t);
    for (int t = t0 + tid; t < t1; t += 1024)
        atomicAdd(&h[obj[t] >> CBLOG], 1);
    __syncthreads();
    if (tid < nb) sbase[tid] = atomicAdd(&gcur[tid], h[tid]);
    __syncthreads();
    if (tid < 256) h[tid] = 0;        // reuse as rank counters
    __syncthreads();
    for (int t = t0 + tid; t < t1; t += 1024) {
        int o = obj[t];
        int bin = o >> CBLOG;
        int rank = atomicAdd(&h[bin], 1);
        packed2[sbase[bin] + rank] = make_uint2(
            (unsigned)subj[t] | ((unsigned)rel[t] << 19), (unsigned)o);
    }
}

// fine counting sort by obj&2047 within each 2048-entity bucket.
__global__ void fine_sort_kernel(const uint2* __restrict__ in,
                                 uint2* __restrict__ outp,
                                 const int* __restrict__ base,
                                 int n_t, int nb) {
    __shared__ int cnt[FNB];
    __shared__ int cur[FNB];
    __shared__ int ws[16];
    int bin = blockIdx.x;
    int beg = base[bin];
    int end = base[bin + 1];
    int t = threadIdx.x;
    int wave = t >> 6, lane = t & 63;
    cnt[t] = 0;
    cnt[t + 1024] = 0;
    __syncthreads();
    for (int i = beg + t; i < end; i += 1024)
        atomicAdd(&cnt[in[i].y & (FNB - 1)], 1);
    __syncthreads();
    int c0 = cnt[2 * t], c1 = cnt[2 * t + 1];
    int pair = c0 + c1;
    int v = pair;
#pragma unroll
    for (int off = 1; off < 64; off <<= 1) {
        int u = __shfl_up(v, off, 64);
        if (lane >= off) v += u;
    }
    if (lane == 63) ws[wave] = v;
    __syncthreads();
    if (wave == 0 && lane < 16) {
        int w = ws[lane];
#pragma unroll
        for (int off = 1; off < 16; off <<= 1) {
            int u = __shfl_up(w, off, 64);
            if (lane >= off) w += u;
        }
        ws[lane] = w;
    }
    __syncthreads();
    int waveOff = (wave == 0) ? 0 : ws[wave - 1];
    int exclPair = waveOff + v - pair;
    cur[2 * t]     = beg + exclPair;
    cur[2 * t + 1] = beg + exclPair + c0;
    __syncthreads();
    for (int i = beg + t; i < end; i += 1024) {
        uint2 e = in[i];
        int pos = atomicAdd(&cur[e.y & (FNB - 1)], 1);
        outp[pos] = e;
    }
}

// Flat hop over SORTED triples: EXACT round-3 inner code (L3/fabric
// random-line bound, FETCH ~118MB invariant r3-r6 -- do not touch).
// Tail zero-blocks fold the next hop's memset into spare BW.
__global__ void hop_merge_kernel(const __half2* __restrict__ xT2,
                                 const float2* __restrict__ rT2,
                                 __half2* __restrict__ outT2,
                                 const uint2* __restrict__ sorted2,
                                 const int* __restrict__ n_hop,
                                 int hop, int n_e, int n_t, int hb,
                                 float4* __restrict__ zptr, long zn4) {
    int tid = threadIdx.x;
    if (blockIdx.x >= hb) {           // ---- zero-blocks ----
        int zb = gridDim.x - hb;
        float4 z4 = make_float4(0.f, 0.f, 0.f, 0.f);
        for (long i = (long)(blockIdx.x - hb) * 256 + tid; i < zn4;
             i += (long)zb * 256)
            zptr[i] = z4;
        return;
    }
    if (*n_hop < hop) {               // degenerate: identity copy
        long total = (long)n_e * 16;
        for (long i = (long)blockIdx.x * 256 + tid; i < total;
             i += (long)hb * 256)
            outT2[i] = xT2[i];
        return;
    }
    __shared__ uint2 ent[256];
    int base = blockIdx.x * 256;
    int cnt = min(256, n_t - base);
    ent[tid] = (tid < cnt) ? sorted2[base + tid]
                           : make_uint2(0u, 0xFFFFFFFFu);
    __syncthreads();
    int g = tid >> 4, l = tid & 15;
    int e0 = g * 16;
    int m = min(16, cnt - e0);        // group-uniform
    if (m <= 0) return;

    __half2 xh[16];
#pragma unroll
    for (int j = 0; j < 16; ++j) {    // independent gathers, all in flight
        int s = (int)(ent[e0 + j].x & 0x7FFFF);
        xh[j] = xT2[(size_t)s * 16 + l];
    }

    float a0 = 0.f, a1 = 0.f;
    unsigned cur_o = ent[e0].y;
#pragma unroll
    for (int j = 0; j < 16; ++j) {
        if (j < m) {
            uint2 e = ent[e0 + j];
            float2 rf = rT2[(size_t)(e.x >> 19) * 16 + l];   // L1-resident
            float2 xf = __half22float2(xh[j]);
            if (e.y != cur_o) {                  // uniform within 16-lane group
                unsafeAtomicAdd(&outT2[(size_t)cur_o * 16 + l],
                                __floats2half2_rn(a0, a1));
                a0 = 0.f; a1 = 0.f;
                cur_o = e.y;
            }
            a0 += xf.x * rf.x;
            a1 += xf.y * rf.y;
        }
    }
    unsafeAtomicAdd(&outT2[(size_t)cur_o * 16 + l], __floats2half2_rn(a0, a1));
}

extern "C" void kernel_launch(void* const* d_in, const int* in_sizes, int n_in,
                              void* d_out, int out_size, void* d_ws, size_t ws_size,
                              hipStream_t stream) {
    const float* x    = (const float*)d_in[0];
    const float* q    = (const float*)d_in[1];
    const int*   subj = (const int*)d_in[2];
    const int*   rel  = (const int*)d_in[3];
    const int*   obj  = (const int*)d_in[4];
    const float* W1   = (const float*)d_in[5];
    const float* bb1  = (const float*)d_in[6];
    const float* W2   = (const float*)d_in[7];
    const float* bb2  = (const float*)d_in[8];
    const float* W3   = (const float*)d_in[9];
    const float* bb3  = (const float*)d_in[10];
    const int*   n_hop = (const int*)d_in[11];
    float* out = (float*)d_out;

    const int n_e   = in_sizes[0] / B;        // 500000
    const int n_t   = in_sizes[2];            // 2000000
    const int nb    = (n_e + CBSZ - 1) >> CBLOG;   // 245 coarse buckets
    const int chunk = (n_t + NBLK - 1) / NBLK;

    // ws layout (~128.3 MB of >=128 MiB): A,B,C contiguous for bulk zeroing
    char* w = (char*)d_ws;
    __half* bufA    = (__half*)w;                     w += 32000000;  // [N_E,B] f16
    __half* bufB    = (__half*)w;                     w += 32000000;  // [N_E,B] f16
    __half* bufC    = (__half*)w;                     w += 32000000;  // [N_E,B] f16
    float*  rT      = (float*)w;                      w += 76800;     // 3*[N_R,B]
    int*    hist_bb = (int*)w;                        w += 262144;    // [nb*NBLK]
    int*    base    = (int*)w;                        w += 4096;      // [nb+1]
    int*    gcur    = (int*)w;                        w += 4096;      // [nb]
    uint2*  packed2 = (uint2*)w;                      w += 16000000;  // [N_T]
    uint2*  sorted2 = (uint2*)w;                                      // [N_T]

    const int tblocks = (n_e + FTE - 1) / FTE;  // 3907

    // front: transpose_in + coarse count + compute_r + zero(B,C), 1 dispatch
    fused_front_kernel<<<tblocks + 3 * NR + ZBC, 256, 0, stream>>>(
        x, bufA, n_e, obj, hist_bb, n_t, nb, chunk, tblocks,
        q, W1, bb1, W2, bb2, W3, bb3, rT,
        (float4*)bufB, 64000000L / 16);     // B+C contiguous, 64MB

    // --- sort by obj: tiny scan + atomic-reserve scatter + fine sort ---
    bucket_scan_kernel<<<1, 256, 0, stream>>>(hist_bb, base, gcur, nb);
    scatter8_kernel<<<NBLK, 1024, 0, stream>>>(subj, rel, obj, gcur, packed2,
                                               n_t, nb, chunk);
    fine_sort_kernel<<<nb, 1024, 0, stream>>>(packed2, sorted2, base, n_t, nb);

    // --- 3 flat hops A->B->C->A; hop2's tail blocks zero A for hop3 ---
    const int hblocks = (n_t + 255) / 256;    // 7813

    hop_merge_kernel<<<hblocks, 256, 0, stream>>>((const __half2*)bufA,
        (const float2*)(rT + 0 * NR * B), (__half2*)bufB, sorted2, n_hop,
        1, n_e, n_t, hblocks, nullptr, 0);
    hop_merge_kernel<<<hblocks + ZA, 256, 0, stream>>>((const __half2*)bufB,
        (const float2*)(rT + 1 * NR * B), (__half2*)bufC, sorted2, n_hop,
        2, n_e, n_t, hblocks, (float4*)bufA, 32000000L / 16);
    hop_merge_kernel<<<hblocks, 256, 0, stream>>>((const __half2*)bufC,
        (const float2*)(rT + 2 * NR * B), (__half2*)bufA, sorted2, n_hop,
        3, n_e, n_t, hblocks, nullptr, 0);

    transpose_out_kernel<<<(n_e + TBE - 1) / TBE, 256, 0, stream>>>(bufA, out, n_e);
}

// Round 15
// 408.333 us; speedup vs baseline: 1.0104x; 1.0104x over previous
//
#include <hip/hip_runtime.h>
#include <hip/hip_fp16.h>

#define B 32
#define NW2V 300
#define NR 200
#define NBLK 256          // chunks for count/scatter passes
#define CBLOG 11          // coarse bucket = 2048 entities
#define CBSZ  2048
#define FNB   2048        // fine bins (11-bit counting sort)
#define TBE   256         // transpose tile: entities per block
#define ZBC   512         // zero-blocks in fused_front (bufB, 32MB)
#define ZA    512         // zero-blocks in hops 1/2

// Fused front: [0,tblocks) transpose x->xT f16 in 256-entity tiles (blocks
// <NBLK also coarse-count one chunk); [tblocks,+3*NR) compute rT; tail ZBC
// blocks stream-zero bufB ONLY (round-15: bufC's zero moved to hop1's tail;
// round-14 lesson: FF is per-thread-MLP-bound -- 256-tile/8xfloat4 is the
// best measured shape, 60us with 64MB zero, ~50us without).
__global__ void fused_front_kernel(const float* __restrict__ x,
                                   __half* __restrict__ xT, int n_e,
                                   const int* __restrict__ obj,
                                   int* __restrict__ hist_bb,
                                   int n_t, int nb, int chunk, int tblocks,
                                   const float* __restrict__ q,
                                   const float* __restrict__ W1, const float* __restrict__ b1,
                                   const float* __restrict__ W2, const float* __restrict__ b2,
                                   const float* __restrict__ W3, const float* __restrict__ b3,
                                   float* __restrict__ rT,
                                   float4* __restrict__ zptr, long zn4) {
    if (blockIdx.x >= tblocks + 3 * NR) {   // ---- zero bufB ----
        long zid = blockIdx.x - (tblocks + 3 * NR);
        float4 z4 = make_float4(0.f, 0.f, 0.f, 0.f);
        for (long i = zid * 256 + threadIdx.x; i < zn4; i += (long)ZBC * 256)
            zptr[i] = z4;
        return;
    }
    if (blockIdx.x >= tblocks) {      // ---- compute_r part (600 blocks) ----
        int bid = blockIdx.x - tblocks;
        int h = bid / NR;
        int j = bid % NR;
        const float* W    = (h == 0) ? W1 : (h == 1) ? W2 : W3;
        const float* bias = (h == 0) ? b1 : (h == 1) ? b2 : b3;
        int t = threadIdx.x;
        int b  = t & 31;
        int ks = t >> 5;              // 8 k-slices of <=38
        int k0 = ks * 38;
        int k1 = min(NW2V, k0 + 38);
        float acc = 0.f;
        for (int k = k0; k < k1; ++k)
            acc += q[b * NW2V + k] * W[k * NR + j];
        __shared__ float red[8][32];
        red[ks][b] = acc;
        __syncthreads();
        if (ks == 0) {
            float s = bias[j];
#pragma unroll
            for (int r = 0; r < 8; ++r) s += red[r][b];
            rT[h * NR * B + j * B + b] = s;
        }
        return;
    }
    // ---- transpose (+count): 256-entity tile, 8x float4 reg-staged ----
    __shared__ float tile[32][261];
    __shared__ int h[256];
    int t = threadIdx.x;
    int e0 = blockIdx.x * TBE;
    bool full = (e0 + TBE <= n_e);
    if (full) {
        float4 v[8];                  // 128B in flight per thread
#pragma unroll
        for (int p = 0; p < 8; ++p) {
            int idx = p * 256 + t;
            int b = idx >> 6, e4 = (idx & 63) * 4;
            v[p] = *reinterpret_cast<const float4*>(&x[(size_t)b * n_e + e0 + e4]);
        }
#pragma unroll
        for (int p = 0; p < 8; ++p) {
            int idx = p * 256 + t;
            int b = idx >> 6, e4 = (idx & 63) * 4;
            tile[b][e4 + 0] = v[p].x; tile[b][e4 + 1] = v[p].y;
            tile[b][e4 + 2] = v[p].z; tile[b][e4 + 3] = v[p].w;
        }
    } else {
        for (int p = 0; p < 32; ++p) {
            int idx = p * 256 + t;
            int b = idx >> 8, e = idx & 255;
            tile[b][e] = (e0 + e < n_e) ? x[(size_t)b * n_e + e0 + e] : 0.f;
        }
    }
    __syncthreads();
#pragma unroll
    for (int p = 0; p < 8; ++p) {
        int idx = p * 256 + t;
        int e = idx >> 3, bq = (idx & 7) * 4;
        if (full || e0 + e < n_e) {
            __half2 h0 = __floats2half2_rn(tile[bq + 0][e], tile[bq + 1][e]);
            __half2 h1 = __floats2half2_rn(tile[bq + 2][e], tile[bq + 3][e]);
            uint2 pk = make_uint2(*reinterpret_cast<unsigned*>(&h0),
                                  *reinterpret_cast<unsigned*>(&h1));
            *reinterpret_cast<uint2*>(xT + (size_t)(e0 + e) * 32 + bq) = pk;
        }
    }
    if (blockIdx.x < NBLK) {          // fused coarse count, 4-wide unroll
        h[t] = 0;
        __syncthreads();
        int t0 = blockIdx.x * chunk;
        int t1 = min(t0 + chunk, n_t);
        for (int i0 = t0 + t; i0 < t1; i0 += 1024) {
            int o0 = obj[i0];
            int o1 = (i0 + 256 < t1) ? obj[i0 + 256] : -1;
            int o2 = (i0 + 512 < t1) ? obj[i0 + 512] : -1;
            int o3 = (i0 + 768 < t1) ? obj[i0 + 768] : -1;
            atomicAdd(&h[o0 >> CBLOG], 1);
            if (o1 >= 0) atomicAdd(&h[o1 >> CBLOG], 1);
            if (o2 >= 0) atomicAdd(&h[o2 >> CBLOG], 1);
            if (o3 >= 0) atomicAdd(&h[o3 >> CBLOG], 1);
        }
        __syncthreads();
        if (t < nb)
            hist_bb[(size_t)t * NBLK + blockIdx.x] = h[t];
    }
}

// xT [N_E, B] f16 -> out [B, N_E] f32. 4 staged float4 reads, float4 writes.
__global__ void transpose_out_kernel(const __half* __restrict__ xT,
                                     float* __restrict__ out, int n_e) {
    __shared__ float tile[256][33];
    int t = threadIdx.x;
    int e0 = blockIdx.x * TBE;
    bool full = (e0 + TBE <= n_e);
    if (full) {
        float4 v[4];
#pragma unroll
        for (int p = 0; p < 4; ++p) {
            int idx = p * 256 + t;
            int e = idx >> 2, qd = idx & 3;
            v[p] = reinterpret_cast<const float4*>(xT)[(size_t)(e0 + e) * 4 + qd];
        }
#pragma unroll
        for (int p = 0; p < 4; ++p) {
            int idx = p * 256 + t;
            int e = idx >> 2, qd = idx & 3;
            const __half2* hp = reinterpret_cast<const __half2*>(&v[p]);
#pragma unroll
            for (int j = 0; j < 4; ++j) {
                float2 f = __half22float2(hp[j]);
                tile[e][qd * 8 + 2 * j]     = f.x;
                tile[e][qd * 8 + 2 * j + 1] = f.y;
            }
        }
        __syncthreads();
#pragma unroll
        for (int p = 0; p < 8; ++p) {
            int idx = p * 256 + t;
            int b = idx >> 6, e4 = (idx & 63) * 4;
            float4 w = make_float4(tile[e4][b], tile[e4 + 1][b],
                                   tile[e4 + 2][b], tile[e4 + 3][b]);
            *reinterpret_cast<float4*>(&out[(size_t)b * n_e + e0 + e4]) = w;
        }
    } else {
        for (int p = 0; p < 16; ++p) {
            int idx = p * 256 + t;
            int e = idx >> 4, bp = idx & 15;
            if (e0 + e < n_e) {
                __half2 v = reinterpret_cast<const __half2*>(xT)[(size_t)(e0 + e) * 16 + bp];
                float2 f = __half22float2(v);
                tile[e][2 * bp]     = f.x;
                tile[e][2 * bp + 1] = f.y;
            }
        }
        __syncthreads();
        for (int p = 0; p < 32; ++p) {
            int idx = p * 256 + t;
            int b = idx >> 8, e = idx & 255;
            if (e0 + e < n_e)
                out[(size_t)b * n_e + e0 + e] = tile[e][b];
        }
    }
}

// One tiny block: per-bucket totals -> exclusive scan -> base[nb+1], gcur[nb].
__global__ void bucket_scan_kernel(const int* __restrict__ hist_bb,
                                   int* __restrict__ base,
                                   int* __restrict__ gcur, int nb) {
    __shared__ int ws[4];
    int t = threadIdx.x, wave = t >> 6, lane = t & 63;
    int tot = 0;
    if (t < nb) {
        const int4* p = reinterpret_cast<const int4*>(hist_bb + (size_t)t * NBLK);
        for (int c = 0; c < NBLK / 4; ++c) {
            int4 v = p[c];
            tot += v.x + v.y + v.z + v.w;
        }
    }
    int v = tot;
#pragma unroll
    for (int off = 1; off < 64; off <<= 1) {
        int u = __shfl_up(v, off, 64);
        if (lane >= off) v += u;
    }
    if (lane == 63) ws[wave] = v;
    __syncthreads();
    if (wave == 0 && lane < 4) {
        int w = ws[lane];
#pragma unroll
        for (int off = 1; off < 4; off <<= 1) {
            int u = __shfl_up(w, off, 64);
            if (lane >= off) w += u;
        }
        ws[lane] = w;
    }
    __syncthreads();
    int excl = (wave ? ws[wave - 1] : 0) + v - tot;
    if (t < nb) {
        base[t] = excl;
        gcur[t] = excl;
    }
    if (t == nb) base[t] = excl;      // total
}

// coarse scatter into 2048-entity buckets; atomic range reservation in gcur.
__global__ void scatter8_kernel(const int* __restrict__ subj,
                                const int* __restrict__ rel,
                                const int* __restrict__ obj,
                                int* __restrict__ gcur,
                                uint2* __restrict__ packed2,
                                int n_t, int nb, int chunk) {
    __shared__ int h[256];
    __shared__ int sbase[256];
    int tid = threadIdx.x;
    if (tid < 256) h[tid] = 0;
    __syncthreads();
    int t0 = blockIdx.x * chunk;
    int t1 = min(t0 + chunk, n_t);
    for (int t = t0 + tid; t < t1; t += 1024)
        atomicAdd(&h[obj[t] >> CBLOG], 1);
    __syncthreads();
    if (tid < nb) sbase[tid] = atomicAdd(&gcur[tid], h[tid]);
    __syncthreads();
    if (tid < 256) h[tid] = 0;        // reuse as rank counters
    __syncthreads();
    for (int t = t0 + tid; t < t1; t += 1024) {
        int o = obj[t];
        int bin = o >> CBLOG;
        int rank = atomicAdd(&h[bin], 1);
        packed2[sbase[bin] + rank] = make_uint2(
            (unsigned)subj[t] | ((unsigned)rel[t] << 19), (unsigned)o);
    }
}

// fine counting sort by obj&2047 within each 2048-entity bucket.
__global__ void fine_sort_kernel(const uint2* __restrict__ in,
                                 uint2* __restrict__ outp,
                                 const int* __restrict__ base,
                                 int n_t, int nb) {
    __shared__ int cnt[FNB];
    __shared__ int cur[FNB];
    __shared__ int ws[16];
    int bin = blockIdx.x;
    int beg = base[bin];
    int end = base[bin + 1];
    int t = threadIdx.x;
    int wave = t >> 6, lane = t & 63;
    cnt[t] = 0;
    cnt[t + 1024] = 0;
    __syncthreads();
    for (int i = beg + t; i < end; i += 1024)
        atomicAdd(&cnt[in[i].y & (FNB - 1)], 1);
    __syncthreads();
    int c0 = cnt[2 * t], c1 = cnt[2 * t + 1];
    int pair = c0 + c1;
    int v = pair;
#pragma unroll
    for (int off = 1; off < 64; off <<= 1) {
        int u = __shfl_up(v, off, 64);
        if (lane >= off) v += u;
    }
    if (lane == 63) ws[wave] = v;
    __syncthreads();
    if (wave == 0 && lane < 16) {
        int w = ws[lane];
#pragma unroll
        for (int off = 1; off < 16; off <<= 1) {
            int u = __shfl_up(w, off, 64);
            if (lane >= off) w += u;
        }
        ws[lane] = w;
    }
    __syncthreads();
    int waveOff = (wave == 0) ? 0 : ws[wave - 1];
    int exclPair = waveOff + v - pair;
    cur[2 * t]     = beg + exclPair;
    cur[2 * t + 1] = beg + exclPair + c0;
    __syncthreads();
    for (int i = beg + t; i < end; i += 1024) {
        uint2 e = in[i];
        int pos = atomicAdd(&cur[e.y & (FNB - 1)], 1);
        outp[pos] = e;
    }
}

// Flat hop over SORTED triples: EXACT round-3 inner code (L3/fabric
// random-line bound, FETCH ~118MB invariant r3-r6 -- do not touch).
// Tail zero-blocks fold a later buffer's memset into spare BW.
__global__ void hop_merge_kernel(const __half2* __restrict__ xT2,
                                 const float2* __restrict__ rT2,
                                 __half2* __restrict__ outT2,
                                 const uint2* __restrict__ sorted2,
                                 const int* __restrict__ n_hop,
                                 int hop, int n_e, int n_t, int hb,
                                 float4* __restrict__ zptr, long zn4) {
    int tid = threadIdx.x;
    if (blockIdx.x >= hb) {           // ---- zero-blocks ----
        int zb = gridDim.x - hb;
        float4 z4 = make_float4(0.f, 0.f, 0.f, 0.f);
        for (long i = (long)(blockIdx.x - hb) * 256 + tid; i < zn4;
             i += (long)zb * 256)
            zptr[i] = z4;
        return;
    }
    if (*n_hop < hop) {               // degenerate: identity copy
        long total = (long)n_e * 16;
        for (long i = (long)blockIdx.x * 256 + tid; i < total;
             i += (long)hb * 256)
            outT2[i] = xT2[i];
        return;
    }
    __shared__ uint2 ent[256];
    int base = blockIdx.x * 256;
    int cnt = min(256, n_t - base);
    ent[tid] = (tid < cnt) ? sorted2[base + tid]
                           : make_uint2(0u, 0xFFFFFFFFu);
    __syncthreads();
    int g = tid >> 4, l = tid & 15;
    int e0 = g * 16;
    int m = min(16, cnt - e0);        // group-uniform
    if (m <= 0) return;

    __half2 xh[16];
#pragma unroll
    for (int j = 0; j < 16; ++j) {    // independent gathers, all in flight
        int s = (int)(ent[e0 + j].x & 0x7FFFF);
        xh[j] = xT2[(size_t)s * 16 + l];
    }

    float a0 = 0.f, a1 = 0.f;
    unsigned cur_o = ent[e0].y;
#pragma unroll
    for (int j = 0; j < 16; ++j) {
        if (j < m) {
            uint2 e = ent[e0 + j];
            float2 rf = rT2[(size_t)(e.x >> 19) * 16 + l];   // L1-resident
            float2 xf = __half22float2(xh[j]);
            if (e.y != cur_o) {                  // uniform within 16-lane group
                unsafeAtomicAdd(&outT2[(size_t)cur_o * 16 + l],
                                __floats2half2_rn(a0, a1));
                a0 = 0.f; a1 = 0.f;
                cur_o = e.y;
            }
            a0 += xf.x * rf.x;
            a1 += xf.y * rf.y;
        }
    }
    unsafeAtomicAdd(&outT2[(size_t)cur_o * 16 + l], __floats2half2_rn(a0, a1));
}

extern "C" void kernel_launch(void* const* d_in, const int* in_sizes, int n_in,
                              void* d_out, int out_size, void* d_ws, size_t ws_size,
                              hipStream_t stream) {
    const float* x    = (const float*)d_in[0];
    const float* q    = (const float*)d_in[1];
    const int*   subj = (const int*)d_in[2];
    const int*   rel  = (const int*)d_in[3];
    const int*   obj  = (const int*)d_in[4];
    const float* W1   = (const float*)d_in[5];
    const float* bb1  = (const float*)d_in[6];
    const float* W2   = (const float*)d_in[7];
    const float* bb2  = (const float*)d_in[8];
    const float* W3   = (const float*)d_in[9];
    const float* bb3  = (const float*)d_in[10];
    const int*   n_hop = (const int*)d_in[11];
    float* out = (float*)d_out;

    const int n_e   = in_sizes[0] / B;        // 500000
    const int n_t   = in_sizes[2];            // 2000000
    const int nb    = (n_e + CBSZ - 1) >> CBLOG;   // 245 coarse buckets
    const int chunk = (n_t + NBLK - 1) / NBLK;

    // ws layout (~128.3 MB of >=128 MiB)
    char* w = (char*)d_ws;
    __half* bufA    = (__half*)w;                     w += 32000000;  // [N_E,B] f16
    __half* bufB    = (__half*)w;                     w += 32000000;  // [N_E,B] f16
    __half* bufC    = (__half*)w;                     w += 32000000;  // [N_E,B] f16
    float*  rT      = (float*)w;                      w += 76800;     // 3*[N_R,B]
    int*    hist_bb = (int*)w;                        w += 262144;    // [nb*NBLK]
    int*    base    = (int*)w;                        w += 4096;      // [nb+1]
    int*    gcur    = (int*)w;                        w += 4096;      // [nb]
    uint2*  packed2 = (uint2*)w;                      w += 16000000;  // [N_T]
    uint2*  sorted2 = (uint2*)w;                                      // [N_T]

    const int tblocks = (n_e + TBE - 1) / TBE;  // 1954

    // front: transpose_in + coarse count + compute_r + zero(B), 1 dispatch
    fused_front_kernel<<<tblocks + 3 * NR + ZBC, 256, 0, stream>>>(
        x, bufA, n_e, obj, hist_bb, n_t, nb, chunk, tblocks,
        q, W1, bb1, W2, bb2, W3, bb3, rT,
        (float4*)bufB, 32000000L / 16);

    // --- sort by obj: tiny scan + atomic-reserve scatter + fine sort ---
    bucket_scan_kernel<<<1, 256, 0, stream>>>(hist_bb, base, gcur, nb);
    scatter8_kernel<<<NBLK, 1024, 0, stream>>>(subj, rel, obj, gcur, packed2,
                                               n_t, nb, chunk);
    fine_sort_kernel<<<nb, 1024, 0, stream>>>(packed2, sorted2, base, n_t, nb);

    // --- hops A->B->C->A; hop1's tail zeros C, hop2's tail zeros A ---
    const int hblocks = (n_t + 255) / 256;    // 7813

    hop_merge_kernel<<<hblocks + ZA, 256, 0, stream>>>((const __half2*)bufA,
        (const float2*)(rT + 0 * NR * B), (__half2*)bufB, sorted2, n_hop,
        1, n_e, n_t, hblocks, (float4*)bufC, 32000000L / 16);
    hop_merge_kernel<<<hblocks + ZA, 256, 0, stream>>>((const __half2*)bufB,
        (const float2*)(rT + 1 * NR * B), (__half2*)bufC, sorted2, n_hop,
        2, n_e, n_t, hblocks, (float4*)bufA, 32000000L / 16);
    hop_merge_kernel<<<hblocks, 256, 0, stream>>>((const __half2*)bufC,
        (const float2*)(rT + 2 * NR * B), (__half2*)bufA, sorted2, n_hop,
        3, n_e, n_t, hblocks, nullptr, 0);

    transpose_out_kernel<<<(n_e + TBE - 1) / TBE, 256, 0, stream>>>(bufA, out, n_e);
}